// Round 9
// baseline (142.733 us; speedup 1.0000x reference)
//
#include <hip/hip_runtime.h>
#include <math.h>

#define B 64
#define N 16384
#define MDIM 64
#define DDIM 512
#define EPSF 1e-16f
#define NCH 32              // chunks per batch
#define CHUNK 512           // rows per chunk
#define GB 16               // batches per group
#define NG (B / GB)         // 4 groups
#define GBLK (GB * NCH)     // 512 blocks per group
#define GRID (B * NCH)      // 2048

typedef float f4 __attribute__((ext_vector_type(4)));

// ws float layout
#define K_OFF      0                        // B*64
#define SCAL_OFF   (B*64)                   // B*8: kn,beta,g,s0,s1,s2,gamma,pad
#define SCORE_OFF  (SCAL_OFF + B*8)         // B*N scores
#define MS_OFF     (SCORE_OFF + B*N)        // B*NCH*2 per-chunk (max, sumexp)
#define PSUM_OFF   (MS_OFF + B*NCH*2)       // B*NCH per-chunk pow partial sums
#define PART_OFF   (PSUM_OFF + B*NCH)       // GRID*64 r partials (unnormalized)

// 16-lane (DPP row) sum reduction: row_ror 8,4,2,1. All 16 lanes end with the sum.
__device__ __forceinline__ float rowsum16(float x) {
    float t;
    t = __int_as_float(__builtin_amdgcn_update_dpp(0, __float_as_int(x), 0x128, 0xF, 0xF, true)); x += t;
    t = __int_as_float(__builtin_amdgcn_update_dpp(0, __float_as_int(x), 0x124, 0xF, 0xF, true)); x += t;
    t = __int_as_float(__builtin_amdgcn_update_dpp(0, __float_as_int(x), 0x122, 0xF, 0xF, true)); x += t;
    t = __int_as_float(__builtin_amdgcn_update_dpp(0, __float_as_int(x), 0x121, 0xF, 0xF, true)); x += t;
    return x;
}

// ---------- K1: o = c@W.T + b, activations ----------
__global__ __launch_bounds__(256) void k1(const float* __restrict__ c,
                                          const float* __restrict__ W,
                                          const float* __restrict__ bias,
                                          float* __restrict__ ws) {
    int b = blockIdx.x;
    __shared__ float cs[DDIM];
    __shared__ float osh[72];
    int tid = threadIdx.x;
    for (int i = tid; i < DDIM; i += 256) cs[i] = c[b * DDIM + i];
    __syncthreads();
    int wave = tid >> 6, lane = tid & 63;
    for (int j = wave; j < MDIM + 6; j += 4) {
        const float* wr = W + (size_t)j * DDIM;
        float sum = 0.f;
        for (int d = lane; d < DDIM; d += 64) sum += cs[d] * wr[d];
        for (int off = 32; off > 0; off >>= 1) sum += __shfl_xor(sum, off);
        if (lane == 0) osh[j] = sum + bias[j];
    }
    __syncthreads();
    if (tid < 64) ws[K_OFF + b * 64 + tid] = osh[tid];
    if (wave == 0) {
        float v = osh[lane];
        float sq = v * v;
        for (int off = 32; off > 0; off >>= 1) sq += __shfl_xor(sq, off);
        if (lane == 0) {
            float kn = sqrtf(sq);
            float ob = osh[64], og = osh[65], os0 = osh[66], os1 = osh[67],
                  os2 = osh[68], ogm = osh[69];
            float beta  = fmaxf(ob, 0.f) + log1pf(expf(-fabsf(ob)));
            float g     = 1.f / (1.f + expf(-og));
            float mx    = fmaxf(os0, fmaxf(os1, os2));
            float e0 = expf(os0 - mx), e1 = expf(os1 - mx), e2 = expf(os2 - mx);
            float es = e0 + e1 + e2;
            float gamma = 1.f + fmaxf(ogm, 0.f) + log1pf(expf(-fabsf(ogm)));
            float* sc = ws + SCAL_OFF + b * 8;
            sc[0] = kn; sc[1] = beta; sc[2] = g;
            sc[3] = e0 / es; sc[4] = e1 / es; sc[5] = e2 / es;
            sc[6] = gamma;
        }
    }
}

// ---------- k2 body: scores + per-chunk softmax stats ----------
__device__ __forceinline__ void k2_body(int b, int chunk,
                                        const float* __restrict__ mem,
                                        float* __restrict__ ws) {
    __shared__ float ks[64];
    __shared__ float kb2[2];
    __shared__ float scbuf[CHUNK];
    int tid = threadIdx.x;
    if (tid < 64) ks[tid] = ws[K_OFF + b * 64 + tid];
    if (tid == 64) kb2[0] = ws[SCAL_OFF + b * 8 + 0];
    if (tid == 65) kb2[1] = ws[SCAL_OFF + b * 8 + 1];
    __syncthreads();
    float kn = kb2[0], beta = kb2[1];
    int grp = tid >> 4, ll = tid & 15;
    float k0 = ks[ll * 4], k1v = ks[ll * 4 + 1], k2v = ks[ll * 4 + 2], k3v = ks[ll * 4 + 3];
    int row0 = chunk * CHUNK;
    #pragma unroll 8
    for (int it = 0; it < CHUNK / 16; ++it) {
        int lrow = it * 16 + grp;
        float4 v = *reinterpret_cast<const float4*>(
            mem + ((size_t)b * N + row0 + lrow) * MDIM + ll * 4);
        float dot = v.x * k0 + v.y * k1v + v.z * k2v + v.w * k3v;
        float sq  = v.x * v.x + v.y * v.y + v.z * v.z + v.w * v.w;
        dot = rowsum16(dot);
        sq  = rowsum16(sq);
        if (ll == 0)
            scbuf[lrow] = beta * (dot / (kn * sqrtf(sq) + EPSF));
    }
    __syncthreads();
    {
        float s0v = scbuf[tid], s1v = scbuf[tid + 256];
        float* sco = ws + SCORE_OFF + (size_t)b * N + row0;
        sco[tid] = s0v;
        sco[tid + 256] = s1v;
    }
    if (tid < 64) {
        float vr[8];
        float m = -1e30f;
        #pragma unroll
        for (int j = 0; j < 8; ++j) {
            vr[j] = scbuf[tid + 64 * j];
            m = fmaxf(m, vr[j]);
        }
        #pragma unroll
        for (int off = 32; off > 0; off >>= 1) m = fmaxf(m, __shfl_xor(m, off));
        float s = 0.f;
        #pragma unroll
        for (int j = 0; j < 8; ++j) s += __expf(vr[j] - m);
        #pragma unroll
        for (int off = 32; off > 0; off >>= 1) s += __shfl_xor(s, off);
        if (tid == 0) {
            ws[MS_OFF + ((size_t)b * NCH + chunk) * 2]     = m;
            ws[MS_OFF + ((size_t)b * NCH + chunk) * 2 + 1] = s;
        }
    }
}

// ---------- krw body: stats combine + w_g/shift/pow + r-partial (L3-hit pass) ----------
__device__ __forceinline__ void krw_body(int b, int chunk,
                                         const float* __restrict__ mem,
                                         const float* __restrict__ w_prev,
                                         float* __restrict__ ws,
                                         float* __restrict__ w_out,
                                         float* __restrict__ part) {
    int tid = threadIdx.x, wave = tid >> 6, lane = tid & 63;
    int grp = tid >> 4, ll = tid & 15;
    __shared__ float wgL[CHUNK + 2];
    __shared__ float wpl[CHUNK];
    __shared__ float lds[16][64];
    __shared__ float red[4];
    int row0 = chunk * CHUNK;

    // issue first mem loads before the prologue
    const f4* mbase = (const f4*)(mem + ((size_t)b * N + row0 + grp) * MDIM + ll * 4);
    f4 pre[4];
    #pragma unroll
    for (int j = 0; j < 4; ++j) pre[j] = mbase[j * 256];

    const float* sl = ws + SCAL_OFF + b * 8;
    float g = sl[2], s0 = sl[3], s1 = sl[4], s2 = sl[5], gamma = sl[6];

    // wave-parallel online-softmax combine (lanes 0..31 hold chunk stats)
    const float* msp = ws + MS_OFF + (size_t)b * NCH * 2;
    float mi = -1e30f, si = 0.f;
    if (lane < NCH) {
        mi = msp[lane * 2];
        si = msp[lane * 2 + 1];
    }
    #pragma unroll
    for (int off = 32; off > 0; off >>= 1) {
        float m2 = __shfl_xor(mi, off), s2x = __shfl_xor(si, off);
        float M = fmaxf(mi, m2);
        si = si * __expf(mi - M) + s2x * __expf(m2 - M);
        mi = M;
    }
    float mx = mi;
    float inv = 1.f / si;

    const float* sc = ws + SCORE_OFF + (size_t)b * N;
    const float* wp = w_prev + (size_t)b * N;

    {
        int r0 = row0 + tid;
        wgL[tid + 1]   = g * (__expf(sc[r0] - mx) * inv) + (1.f - g) * wp[r0];
        int r1 = row0 + tid + 256;
        wgL[tid + 257] = g * (__expf(sc[r1] - mx) * inv) + (1.f - g) * wp[r1];
        if (tid == 0) {
            int rl = (row0 - 1) & (N - 1);
            wgL[0] = g * (__expf(sc[rl] - mx) * inv) + (1.f - g) * wp[rl];
        }
        if (tid == 255) {
            int rr = (row0 + CHUNK) & (N - 1);
            wgL[CHUNK + 1] = g * (__expf(sc[rr] - mx) * inv) + (1.f - g) * wp[rr];
        }
    }
    __syncthreads();

    float wt0 = s0 * wgL[tid]       + s1 * wgL[tid + 1]   + s2 * wgL[tid + 2];
    float wt1 = s0 * wgL[tid + 256] + s1 * wgL[tid + 257] + s2 * wgL[tid + 258];
    float p0 = __expf(gamma * __logf(wt0));
    float p1 = __expf(gamma * __logf(wt1));
    wpl[tid] = p0;
    wpl[tid + 256] = p1;
    float* wo = w_out + (size_t)b * N + row0;
    wo[tid]       = p0;
    wo[tid + 256] = p1;

    float sp = p0 + p1;
    #pragma unroll
    for (int off = 32; off > 0; off >>= 1) sp += __shfl_xor(sp, off);
    if (lane == 0) red[wave] = sp;
    __syncthreads();
    if (tid == 0)
        ws[PSUM_OFF + (size_t)b * NCH + chunk] = red[0] + red[1] + red[2] + red[3];

    // memory pass (should be L3-resident): software-pipelined
    f4 acc = (f4)(0.f);
    #pragma unroll
    for (int it = 0; it < CHUNK / 16; ++it) {
        f4 v = pre[it & 3];
        int nxt = it + 4;
        if (nxt < CHUNK / 16) pre[it & 3] = mbase[nxt * 256];
        float wv = wpl[it * 16 + grp];
        acc += wv * v;
    }
    lds[grp][ll * 4 + 0] = acc.x;
    lds[grp][ll * 4 + 1] = acc.y;
    lds[grp][ll * 4 + 2] = acc.z;
    lds[grp][ll * 4 + 3] = acc.w;
    __syncthreads();
    if (tid < 64) {
        float sacc = 0.f;
        #pragma unroll
        for (int gi = 0; gi < 16; ++gi) sacc += lds[gi][tid];
        part[((size_t)b * NCH + chunk) * 64 + tid] = sacc;
    }
}

// ---------- group kernels ----------
__global__ __launch_bounds__(256, 8) void k2k(const float* __restrict__ mem,
                                              float* __restrict__ ws, int b0) {
    k2_body(b0 + (blockIdx.x >> 5), blockIdx.x & 31, mem, ws);
}

__global__ __launch_bounds__(256, 8) void krwk(const float* __restrict__ mem,
                                               const float* __restrict__ w_prev,
                                               float* __restrict__ ws,
                                               float* __restrict__ w_out,
                                               float* __restrict__ part, int b0) {
    krw_body(b0 + (blockIdx.x >> 5), blockIdx.x & 31, mem, w_prev, ws, w_out, part);
}

// mixed: blocks [0,GBLK) stream NEW group from HBM (k2); [GBLK,2*GBLK) do krw
// on the JUST-TOUCHED group (L3 hits). Different batches -> independent.
__global__ __launch_bounds__(256, 8) void kmix(const float* __restrict__ mem,
                                               const float* __restrict__ w_prev,
                                               float* __restrict__ ws,
                                               float* __restrict__ w_out,
                                               float* __restrict__ part,
                                               int k2_b0, int krw_b0) {
    int bid = blockIdx.x;
    if (bid < GBLK) {
        k2_body(k2_b0 + (bid >> 5), bid & 31, mem, ws);
    } else {
        bid -= GBLK;
        krw_body(krw_b0 + (bid >> 5), bid & 31, mem, w_prev, ws, w_out, part);
    }
}

// ---------- KFIN: invp; finalize w in place; chunk-0 blocks also emit r ----------
__global__ __launch_bounds__(256) void kfin(const float* __restrict__ part,
                                            float* __restrict__ ws,
                                            float* __restrict__ w_out,
                                            float* __restrict__ r) {
    int b = blockIdx.x >> 5, chunk = blockIdx.x & 31;
    int tid = threadIdx.x;
    __shared__ float invps;
    if (tid < 64) {
        float s = (tid < 32) ? ws[PSUM_OFF + (size_t)b * NCH + tid] : 0.f;
        #pragma unroll
        for (int off = 32; off > 0; off >>= 1) s += __shfl_xor(s, off);
        if (tid == 0) invps = 1.f / (s + EPSF);
    }
    __syncthreads();
    float invp = invps;
    size_t base = (size_t)b * N + chunk * CHUNK;
    w_out[base + tid]       *= invp;
    w_out[base + tid + 256] *= invp;
    if (chunk == 0 && tid < 64) {
        float srr = 0.f;
        #pragma unroll
        for (int c2 = 0; c2 < NCH; ++c2)
            srr += part[((size_t)b * NCH + c2) * 64 + tid];
        r[b * 64 + tid] = srr * invp;
    }
}

extern "C" void kernel_launch(void* const* d_in, const int* in_sizes, int n_in,
                              void* d_out, int out_size, void* d_ws, size_t ws_size,
                              hipStream_t stream) {
    const float* c      = (const float*)d_in[0];
    const float* w_prev = (const float*)d_in[1];
    const float* mem    = (const float*)d_in[2];
    const float* W      = (const float*)d_in[3];
    const float* bias   = (const float*)d_in[4];
    float* out = (float*)d_out;
    float* r_out = out;                 // B*M
    float* w_out = out + B * MDIM;      // B*N (staged as w_pow, finalized by kfin)
    float* ws = (float*)d_ws;
    float* part = ws + PART_OFF;

    k1  <<<B,        256, 0, stream>>>(c, W, bias, ws);
    k2k <<<GBLK,     256, 0, stream>>>(mem, ws, 0);
    kmix<<<2 * GBLK, 256, 0, stream>>>(mem, w_prev, ws, w_out, part, GB,     0);
    kmix<<<2 * GBLK, 256, 0, stream>>>(mem, w_prev, ws, w_out, part, 2 * GB, GB);
    kmix<<<2 * GBLK, 256, 0, stream>>>(mem, w_prev, ws, w_out, part, 3 * GB, 2 * GB);
    krwk<<<GBLK,     256, 0, stream>>>(mem, w_prev, ws, w_out, part, 3 * GB);
    kfin<<<GRID,     256, 0, stream>>>(part, ws, w_out, r_out);
}

// Round 10
// 106.353 us; speedup vs baseline: 1.3421x; 1.3421x over previous
//
#include <hip/hip_runtime.h>
#include <math.h>

#define B 64
#define N 16384
#define MDIM 64
#define DDIM 512
#define EPSF 1e-16f
#define NCH 32              // chunks per batch
#define CHUNK 512           // rows per chunk
#define GRID (B * NCH)      // 2048 blocks

typedef float f4 __attribute__((ext_vector_type(4)));
typedef float f2 __attribute__((ext_vector_type(2)));

// ws float layout
#define K_OFF      0                        // B*64
#define SCAL_OFF   (B*64)                   // B*8: kn,beta,g,s0,s1,s2,gamma,pad
#define SCORE_OFF  (SCAL_OFF + B*8)         // B*N scores
#define MS_OFF     (SCORE_OFF + B*N)        // B*NCH*2 per-chunk (max, sumexp)
#define PSUM_OFF   (MS_OFF + B*NCH*2)       // B*NCH per-chunk pow partial sums
#define PART_OFF   (PSUM_OFF + B*NCH)       // GRID*64 r partials (unnormalized)

// 16-lane (DPP row) sum reduction: row_ror 8,4,2,1. All 16 lanes end with the sum.
__device__ __forceinline__ float rowsum16(float x) {
    float t;
    t = __int_as_float(__builtin_amdgcn_update_dpp(0, __float_as_int(x), 0x128, 0xF, 0xF, true)); x += t;
    t = __int_as_float(__builtin_amdgcn_update_dpp(0, __float_as_int(x), 0x124, 0xF, 0xF, true)); x += t;
    t = __int_as_float(__builtin_amdgcn_update_dpp(0, __float_as_int(x), 0x122, 0xF, 0xF, true)); x += t;
    t = __int_as_float(__builtin_amdgcn_update_dpp(0, __float_as_int(x), 0x121, 0xF, 0xF, true)); x += t;
    return x;
}

// ---------- K1: o = c@W.T + b, activations ----------
__global__ __launch_bounds__(256) void k1(const float* __restrict__ c,
                                          const float* __restrict__ W,
                                          const float* __restrict__ bias,
                                          float* __restrict__ ws) {
    int b = blockIdx.x;
    __shared__ float cs[DDIM];
    __shared__ float osh[72];
    int tid = threadIdx.x;
    for (int i = tid; i < DDIM; i += 256) cs[i] = c[b * DDIM + i];
    __syncthreads();
    int wave = tid >> 6, lane = tid & 63;
    for (int j = wave; j < MDIM + 6; j += 4) {
        const float* wr = W + (size_t)j * DDIM;
        float sum = 0.f;
        for (int d = lane; d < DDIM; d += 64) sum += cs[d] * wr[d];
        for (int off = 32; off > 0; off >>= 1) sum += __shfl_xor(sum, off);
        if (lane == 0) osh[j] = sum + bias[j];
    }
    __syncthreads();
    if (tid < 64) ws[K_OFF + b * 64 + tid] = osh[tid];
    if (wave == 0) {
        float v = osh[lane];
        float sq = v * v;
        for (int off = 32; off > 0; off >>= 1) sq += __shfl_xor(sq, off);
        if (lane == 0) {
            float kn = sqrtf(sq);
            float ob = osh[64], og = osh[65], os0 = osh[66], os1 = osh[67],
                  os2 = osh[68], ogm = osh[69];
            float beta  = fmaxf(ob, 0.f) + log1pf(expf(-fabsf(ob)));
            float g     = 1.f / (1.f + expf(-og));
            float mx    = fmaxf(os0, fmaxf(os1, os2));
            float e0 = expf(os0 - mx), e1 = expf(os1 - mx), e2 = expf(os2 - mx);
            float es = e0 + e1 + e2;
            float gamma = 1.f + fmaxf(ogm, 0.f) + log1pf(expf(-fabsf(ogm)));
            float* sc = ws + SCAL_OFF + b * 8;
            sc[0] = kn; sc[1] = beta; sc[2] = g;
            sc[3] = e0 / es; sc[4] = e1 / es; sc[5] = e2 / es;
            sc[6] = gamma;
        }
    }
}

// ---------- K2: scores + per-chunk softmax stats (prefetch-pipelined, NT) ----------
__global__ __launch_bounds__(256, 8) void k2(const float* __restrict__ mem,
                                             float* __restrict__ ws) {
    int b = blockIdx.x >> 5, chunk = blockIdx.x & 31;
    __shared__ float ks[64];
    __shared__ float kb2[2];
    __shared__ float scbuf[CHUNK];
    int tid = threadIdx.x;
    int grp = tid >> 4, ll = tid & 15;
    int row0 = chunk * CHUNK;

    // issue first mem loads before anything else
    const f4* mbase = (const f4*)(mem + ((size_t)b * N + row0 + grp) * MDIM + ll * 4);
    f4 pre[4];
    #pragma unroll
    for (int j = 0; j < 4; ++j)
        pre[j] = __builtin_nontemporal_load(mbase + j * 256);

    if (tid < 64) ks[tid] = ws[K_OFF + b * 64 + tid];
    if (tid == 64) kb2[0] = ws[SCAL_OFF + b * 8 + 0];
    if (tid == 65) kb2[1] = ws[SCAL_OFF + b * 8 + 1];
    __syncthreads();
    float kn = kb2[0], beta = kb2[1];
    float k0 = ks[ll * 4], k1v = ks[ll * 4 + 1], k2v = ks[ll * 4 + 2], k3v = ks[ll * 4 + 3];

    #pragma unroll
    for (int it = 0; it < CHUNK / 16; ++it) {
        f4 v = pre[it & 3];
        int nxt = it + 4;
        if (nxt < CHUNK / 16)
            pre[it & 3] = __builtin_nontemporal_load(mbase + nxt * 256);
        float dot = v.x * k0 + v.y * k1v + v.z * k2v + v.w * k3v;
        float sq  = v.x * v.x + v.y * v.y + v.z * v.z + v.w * v.w;
        dot = rowsum16(dot);
        sq  = rowsum16(sq);
        if (ll == 0)
            scbuf[it * 16 + grp] = beta * (dot / (kn * sqrtf(sq) + EPSF));
    }
    __syncthreads();
    // coalesced NT score write + chunk stats from wave 0
    {
        float s0v = scbuf[tid], s1v = scbuf[tid + 256];
        float* sco = ws + SCORE_OFF + (size_t)b * N + row0;
        __builtin_nontemporal_store(s0v, sco + tid);
        __builtin_nontemporal_store(s1v, sco + tid + 256);
    }
    if (tid < 64) {
        float vr[8];
        float m = -1e30f;
        #pragma unroll
        for (int j = 0; j < 8; ++j) {
            vr[j] = scbuf[tid + 64 * j];
            m = fmaxf(m, vr[j]);
        }
        #pragma unroll
        for (int off = 32; off > 0; off >>= 1) m = fmaxf(m, __shfl_xor(m, off));
        float s = 0.f;
        #pragma unroll
        for (int j = 0; j < 8; ++j) s += __expf(vr[j] - m);
        #pragma unroll
        for (int off = 32; off > 0; off >>= 1) s += __shfl_xor(s, off);
        if (tid == 0) {
            ws[MS_OFF + ((size_t)b * NCH + chunk) * 2]     = m;
            ws[MS_OFF + ((size_t)b * NCH + chunk) * 2 + 1] = s;
        }
    }
}

// ---------- KRW: prefetch-pipelined w_g/shift/pow + r-partial memory pass ----------
__global__ __launch_bounds__(256, 8) void krw(const float* __restrict__ mem,
                                              const float* __restrict__ w_prev,
                                              float* __restrict__ ws,
                                              float* __restrict__ w_out,
                                              float* __restrict__ part) {
    int b = blockIdx.x >> 5, chunk = blockIdx.x & 31;
    int tid = threadIdx.x, wave = tid >> 6, lane = tid & 63;
    int grp = tid >> 4, ll = tid & 15;
    __shared__ float wgL[CHUNK + 2];   // w_g halo buffer
    __shared__ float wpl[CHUNK];       // w_pow (unnormalized)
    __shared__ float lds[16][64];      // r partial reduce
    __shared__ float red[4];
    int row0 = chunk * CHUNK;

    // ---- issue first mem loads BEFORE the prologue (keep HBM busy) ----
    const f4* mbase = (const f4*)(mem + ((size_t)b * N + row0 + grp) * MDIM + ll * 4);
    f4 pre[4];
    #pragma unroll
    for (int j = 0; j < 4; ++j)
        pre[j] = __builtin_nontemporal_load(mbase + j * 256);

    const float* sl = ws + SCAL_OFF + b * 8;
    float g = sl[2], s0 = sl[3], s1 = sl[4], s2 = sl[5], gamma = sl[6];

    // ---- wave-parallel online-softmax combine (lanes 0..31 hold pairs) ----
    const float* msp = ws + MS_OFF + (size_t)b * NCH * 2;
    float mi = -1e30f, si = 0.f;
    if (lane < NCH) {
        mi = msp[lane * 2];
        si = msp[lane * 2 + 1];
    }
    #pragma unroll
    for (int off = 32; off > 0; off >>= 1) {
        float m2 = __shfl_xor(mi, off), s2x = __shfl_xor(si, off);
        float M = fmaxf(mi, m2);
        si = si * __expf(mi - M) + s2x * __expf(m2 - M);
        mi = M;
    }
    float mx = mi;
    float inv = 1.f / si;

    const float* sc = ws + SCORE_OFF + (size_t)b * N;
    const float* wp = w_prev + (size_t)b * N;

    // w_g(row) = g * softmax + (1-g) * w_prev, rows row0-1 .. row0+CHUNK (float2 loads)
    {
        int r0 = row0 + 2 * tid;
        f2 scv = *reinterpret_cast<const f2*>(sc + r0);
        f2 wpv = *reinterpret_cast<const f2*>(wp + r0);
        wgL[2 * tid + 1] = g * (__expf(scv.x - mx) * inv) + (1.f - g) * wpv.x;
        wgL[2 * tid + 2] = g * (__expf(scv.y - mx) * inv) + (1.f - g) * wpv.y;
        if (tid == 0) {
            int rl = (row0 - 1) & (N - 1);
            wgL[0] = g * (__expf(sc[rl] - mx) * inv) + (1.f - g) * wp[rl];
        }
        if (tid == 255) {
            int rr = (row0 + CHUNK) & (N - 1);
            wgL[CHUNK + 1] = g * (__expf(sc[rr] - mx) * inv) + (1.f - g) * wp[rr];
        }
    }
    __syncthreads();

    // shift + pow; stage w_pow in LDS and to w_out (unnormalized, NT)
    float wt0 = s0 * wgL[tid]       + s1 * wgL[tid + 1]   + s2 * wgL[tid + 2];
    float wt1 = s0 * wgL[tid + 256] + s1 * wgL[tid + 257] + s2 * wgL[tid + 258];
    float p0 = __expf(gamma * __logf(wt0));   // wt in (0,1]; ->0 correctly
    float p1 = __expf(gamma * __logf(wt1));
    wpl[tid] = p0;
    wpl[tid + 256] = p1;
    float* wo = w_out + (size_t)b * N + row0;
    __builtin_nontemporal_store(p0, wo + tid);
    __builtin_nontemporal_store(p1, wo + tid + 256);

    // per-chunk pow-sum
    float sp = p0 + p1;
    #pragma unroll
    for (int off = 32; off > 0; off >>= 1) sp += __shfl_xor(sp, off);
    if (lane == 0) red[wave] = sp;
    __syncthreads();
    if (tid == 0)
        ws[PSUM_OFF + (size_t)b * NCH + chunk] = red[0] + red[1] + red[2] + red[3];

    // ---- memory pass: software-pipelined, nontemporal (last use of mem) ----
    f4 acc = (f4)(0.f);
    #pragma unroll
    for (int it = 0; it < CHUNK / 16; ++it) {
        f4 v = pre[it & 3];
        int nxt = it + 4;
        if (nxt < CHUNK / 16)
            pre[it & 3] = __builtin_nontemporal_load(mbase + nxt * 256);
        float wv = wpl[it * 16 + grp];
        acc += wv * v;
    }
    lds[grp][ll * 4 + 0] = acc.x;
    lds[grp][ll * 4 + 1] = acc.y;
    lds[grp][ll * 4 + 2] = acc.z;
    lds[grp][ll * 4 + 3] = acc.w;
    __syncthreads();
    if (tid < 64) {
        float sacc = 0.f;
        #pragma unroll
        for (int gi = 0; gi < 16; ++gi) sacc += lds[gi][tid];
        part[(size_t)blockIdx.x * 64 + tid] = sacc;
    }
}

// ---------- KFIN: invp; finalize w in place; chunk-0 blocks also emit r ----------
__global__ __launch_bounds__(256) void kfin(const float* __restrict__ part,
                                            float* __restrict__ ws,
                                            float* __restrict__ w_out,
                                            float* __restrict__ r) {
    int b = blockIdx.x >> 5, chunk = blockIdx.x & 31;
    int tid = threadIdx.x;
    __shared__ float invps;
    if (tid < 64) {
        float s = (tid < 32) ? ws[PSUM_OFF + (size_t)b * NCH + tid] : 0.f;
        #pragma unroll
        for (int off = 32; off > 0; off >>= 1) s += __shfl_xor(s, off);
        if (tid == 0) invps = 1.f / (s + EPSF);
    }
    __syncthreads();
    float invp = invps;
    size_t base = (size_t)b * N + chunk * CHUNK;
    float a0 = w_out[base + tid] * invp;
    float a1 = w_out[base + tid + 256] * invp;
    __builtin_nontemporal_store(a0, w_out + base + tid);
    __builtin_nontemporal_store(a1, w_out + base + tid + 256);
    if (chunk == 0 && tid < 64) {
        float srr = 0.f;
        #pragma unroll
        for (int c2 = 0; c2 < NCH; ++c2)
            srr += part[((size_t)b * NCH + c2) * 64 + tid];
        r[b * 64 + tid] = srr * invp;
    }
}

extern "C" void kernel_launch(void* const* d_in, const int* in_sizes, int n_in,
                              void* d_out, int out_size, void* d_ws, size_t ws_size,
                              hipStream_t stream) {
    const float* c      = (const float*)d_in[0];
    const float* w_prev = (const float*)d_in[1];
    const float* mem    = (const float*)d_in[2];
    const float* W      = (const float*)d_in[3];
    const float* bias   = (const float*)d_in[4];
    float* out = (float*)d_out;
    float* r_out = out;                 // B*M
    float* w_out = out + B * MDIM;      // B*N (staged as w_pow, finalized by kfin)
    float* ws = (float*)d_ws;
    float* part = ws + PART_OFF;

    k1  <<<B,    256, 0, stream>>>(c, W, bias, ws);
    k2  <<<GRID, 256, 0, stream>>>(mem, ws);
    krw <<<GRID, 256, 0, stream>>>(mem, w_prev, ws, w_out, part);
    kfin<<<GRID, 256, 0, stream>>>(part, ws, w_out, r_out);
}